// Round 8
// baseline (167.587 us; speedup 1.0000x reference)
//
#include <hip/hip_runtime.h>

// (B,P,C,H,W)=(256,10,32,8,8); Tm=19, Ta=10, hw=64. All I/O fp32.
// Horner: A_0=[F_0;1]; A_{p+1}=A_p*M_p+[F_{p+1};1] (p=0..8) -> A_9=[G;W]
// out[b,t,c,j] = (G[c,:].M_t[:,j]) / (W.M_t[:,j] + eps)
//
// v18 (from v17, first MFMA version, 54us): occupancy + duplication fix.
//  - 768 thr = 12 waves, one per (rt,ct) tile of the 48x64 state: 24
//    waves/CU (was 8). Per-wave acc = one f32x4 -> launch_bounds(768,6)
//    caps VGPR at 85 for 6 waves/SIMD.
//  - Mb LDS ring DROPPED: B fragments read straight from global (L2-hot,
//    sibling blocks co-XCD share the M stream). Kills the 3.3M LDS bank
//    conflicts (B b32 reads in a 16-col band were structurally 4-way) and
//    32KB of LDS; 24-wave TLP hides L2 latency.
//  - mm9 -> mm6 (drop a2b3,a3b2,a3b3 ~ 2^-26 rel, below fp32 eps).
//  - At stays fp32 [2][64*49] (stride 49: reads 2-way max, writes clean),
//    one barrier per step. W broadcast via 2-slot Wv ring in output phase.

#define EPSV 1e-6f

typedef short  bf16x8 __attribute__((ext_vector_type(8)));
typedef float  f32x4  __attribute__((ext_vector_type(4)));
typedef unsigned int uintx4 __attribute__((ext_vector_type(4)));

__device__ __forceinline__ unsigned cvtpk(float a, float b) {
    unsigned r;
    asm("v_cvt_pk_bf16_f32 %0, %1, %2" : "=v"(r) : "v"(a), "v"(b));
    return r;
}

// exact 3-way split of 8 fp32 -> three bf16x8 fragments (RNE, non-overlap)
__device__ __forceinline__ void split8(const float* x,
                                       bf16x8& f1, bf16x8& f2, bf16x8& f3) {
    uintx4 w1, w2, w3;
    #pragma unroll
    for (int p = 0; p < 4; ++p) {
        const float x0 = x[2 * p], x1 = x[2 * p + 1];
        const unsigned a = cvtpk(x0, x1);
        const float y0 = x0 - __uint_as_float(a << 16);
        const float y1 = x1 - __uint_as_float(a & 0xffff0000u);
        const unsigned bq = cvtpk(y0, y1);
        const float z0 = y0 - __uint_as_float(bq << 16);
        const float z1 = y1 - __uint_as_float(bq & 0xffff0000u);
        w1[p] = a; w2[p] = bq; w3[p] = cvtpk(z0, z1);
    }
    f1 = __builtin_bit_cast(bf16x8, w1);
    f2 = __builtin_bit_cast(bf16x8, w2);
    f3 = __builtin_bit_cast(bf16x8, w3);
}

#define MFMA __builtin_amdgcn_mfma_f32_16x16x32_bf16

// C += A*B via 6 cross products (small-to-large), fp32 accumulate.
__device__ __forceinline__ f32x4 mm6(f32x4 c,
        bf16x8 a1, bf16x8 a2, bf16x8 a3,
        bf16x8 b1, bf16x8 b2, bf16x8 b3) {
    c = MFMA(a3, b1, c, 0, 0, 0);
    c = MFMA(a1, b3, c, 0, 0, 0);
    c = MFMA(a2, b2, c, 0, 0, 0);
    c = MFMA(a2, b1, c, 0, 0, 0);
    c = MFMA(a1, b2, c, 0, 0, 0);
    c = MFMA(a1, b1, c, 0, 0, 0);
    return c;
}

__global__ __launch_bounds__(768, 6) void k_fused(
    const float* __restrict__ feats,   // (256,10,32,64)
    const float* __restrict__ sim,     // (256,19,64,64)
    float* __restrict__ out)           // (2560,32,64)
{
    __shared__ __attribute__((aligned(16))) float At[2][3136];  // [k*49+row]
    __shared__ float Wv[2][64];

    const int tid  = threadIdx.x;
    const int lane = tid & 63;
    const int wave = tid >> 6;          // 0..11
    const int rt   = wave >> 2;         // row-tile 0..2 (rows 16rt..16rt+15)
    const int ct   = wave & 3;          // col-tile 0..3
    const int lg   = lane >> 4;         // k-subgroup / D-row group
    const int c    = lane & 15;         // A/D col within tile
    const int cb   = 16 * ct + c;       // absolute column
    const int b    = blockIdx.x & 255;  // pair (b, b+256) -> same XCD
    const int h    = blockIdx.x >> 8;   // t-half: t = 5h..5h+4

    const float* fb = feats + (size_t)b * 20480;   // 10*32*64
    const float* sb = sim   + (size_t)b * 77824;   // 19*64*64

    // ---- prologue: At[0] = [F_0; 1; 0-pad]^T ----
    #pragma unroll
    for (int i = 0; i < 4; ++i) {
        const int idx = i * 768 + tid;  // 0..3071 = row*64 + k
        const int row = idx >> 6, k = idx & 63;
        float v = 0.f;
        if (row < 32)       v = fb[row * 64 + k];
        else if (row == 32) v = 1.0f;
        At[0][k * 49 + row] = v;
    }
    __syncthreads();

    // ---- recursion: s=0..8, A_{s+1} = A_s*M_s + [F_{s+1};1;0] ----
    for (int s = 0; s < 9; ++s) {
        const float* __restrict__ Mg = sb + (size_t)s * 4096;

        f32x4 C;
        if (rt < 2) {
            const float* __restrict__ F = fb + (s + 1) * 2048;
            #pragma unroll
            for (int i = 0; i < 4; ++i)
                C[i] = F[(16 * rt + 4 * lg + i) * 64 + cb];
        } else {
            C = (f32x4){0.f, 0.f, 0.f, 0.f};
            if (lg == 0) C[0] = 1.0f;          // W row (row 32): F == 1
        }

        const float* __restrict__ Atc = At[s & 1];
        #pragma unroll
        for (int kh = 0; kh < 2; ++kh) {
            float xb[8];
            #pragma unroll
            for (int j = 0; j < 8; ++j)
                xb[j] = Mg[(32 * kh + 8 * lg + j) * 64 + cb];   // global, L2-hot
            bf16x8 bb1, bb2, bb3; split8(xb, bb1, bb2, bb3);

            float xa[8];
            #pragma unroll
            for (int j = 0; j < 8; ++j)
                xa[j] = Atc[(32 * kh + 8 * lg + j) * 49 + 16 * rt + c];
            bf16x8 a1, a2, a3; split8(xa, a1, a2, a3);

            C = mm6(C, a1, a2, a3, bb1, bb2, bb3);
        }

        // writeback A_{s+1}^T into the other buffer (banks 17c: clean)
        float* __restrict__ Atn = At[(s + 1) & 1];
        #pragma unroll
        for (int i = 0; i < 4; ++i)
            Atn[cb * 49 + 16 * rt + 4 * lg + i] = C[i];
        __syncthreads();
    }

    // ---- G fragments once (A_9 lives in At[1]) ----
    bf16x8 g1[2], g2[2], g3[2];
    #pragma unroll
    for (int kh = 0; kh < 2; ++kh) {
        float xa[8];
        #pragma unroll
        for (int j = 0; j < 8; ++j)
            xa[j] = At[1][(32 * kh + 8 * lg + j) * 49 + 16 * rt + c];
        split8(xa, g1[kh], g2[kh], g3[kh]);
    }

    // ---- output: t = 5h..5h+4, D = [G;W]*M_t, normalize ----
    for (int s = 0; s < 5; ++s) {
        const int t = 5 * h + s;
        const float* __restrict__ Mg = sb + (size_t)(9 + t) * 4096;

        f32x4 C = {0.f, 0.f, 0.f, 0.f};
        #pragma unroll
        for (int kh = 0; kh < 2; ++kh) {
            float xb[8];
            #pragma unroll
            for (int j = 0; j < 8; ++j)
                xb[j] = Mg[(32 * kh + 8 * lg + j) * 64 + cb];
            bf16x8 v1, v2, v3; split8(xb, v1, v2, v3);
            C = mm6(C, g1[kh], g2[kh], g3[kh], v1, v2, v3);
        }

        if (rt == 2 && lg == 0) Wv[s & 1][cb] = C[0];   // row 32 = W.M_t
        __syncthreads();

        if (rt < 2) {
            const float rw = 1.f / (Wv[s & 1][cb] + EPSV);
            float* ob = out + ((size_t)b * 10 + t) * 2048;
            #pragma unroll
            for (int i = 0; i < 4; ++i)
                ob[(16 * rt + 4 * lg + i) * 64 + cb] = C[i] * rw;
        }
    }
}

extern "C" void kernel_launch(void* const* d_in, const int* in_sizes, int n_in,
                              void* d_out, int out_size, void* d_ws, size_t ws_size,
                              hipStream_t stream) {
    const float* feats = (const float*)d_in[0];
    const float* sim   = (const float*)d_in[1];
    k_fused<<<512, 768, 0, stream>>>(feats, sim, (float*)d_out);
}

// Round 9
// 153.741 us; speedup vs baseline: 1.0901x; 1.0901x over previous
//
#include <hip/hip_runtime.h>

// (B,P,C,H,W)=(256,10,32,8,8); Tm=19, Ta=10, hw=64. All I/O fp32.
// Horner: A_0=[F_0;1]; A_{p+1}=A_p*M_p+[F_{p+1};1] (p=0..8) -> A_9=[G;W]
// out[b,t,c,j] = (G[c,:].M_t[:,j]) / (W.M_t[:,j] + eps)
//
// v19 (from v17/v18 post-mortems): row-split recursion for occupancy
// without spill. The recursion is ROW-independent, so:
//  - grid 1024 = 256 b x 2 row-groups (rt) x 2 t-halves (h). Block state =
//    [16 G-channels; W; 15 pad] = 2 MFMA row-tiles; 4 waves (col tiles).
//    4 blocks/CU = 16 waves/CU (2x v17), VGPR cap 128 (launch_bounds 256,4)
//    holds phase-2 G-frags (48 VGPR) spill-free (v17: 88 used).
//  - per wave/step: 1 B-split + 2 A-splits + 2 x mm6 (B-split NOT
//    duplicated across row tiles -- v18's mistake).
//  - W row carried by every block (1 duplicated row ~ free) -> phase-2
//    normalization is a wave-local __shfl; output loop barrier-free.
//  - B read straight from global (L2-hot; v18-proven). Siblings b, b+256,
//    b+512, b+768 are co-XCD (256%8==0) -> shared L2 M-stream.
//  - At[2][64*35] fp32 transposed state, stride 35 (reads/writes <=2-way).
//  - mm6: exact 3-way bf16 split, 6 cross products (v18-proven numerics).

#define EPSV 1e-6f

typedef short  bf16x8 __attribute__((ext_vector_type(8)));
typedef float  f32x4  __attribute__((ext_vector_type(4)));
typedef unsigned int uintx4 __attribute__((ext_vector_type(4)));

__device__ __forceinline__ unsigned cvtpk(float a, float b) {
    unsigned r;
    asm("v_cvt_pk_bf16_f32 %0, %1, %2" : "=v"(r) : "v"(a), "v"(b));
    return r;
}

// exact 3-way split of 8 fp32 -> three bf16x8 fragments (RNE, non-overlap)
__device__ __forceinline__ void split8(const float* x,
                                       bf16x8& f1, bf16x8& f2, bf16x8& f3) {
    uintx4 w1, w2, w3;
    #pragma unroll
    for (int p = 0; p < 4; ++p) {
        const float x0 = x[2 * p], x1 = x[2 * p + 1];
        const unsigned a = cvtpk(x0, x1);
        const float y0 = x0 - __uint_as_float(a << 16);
        const float y1 = x1 - __uint_as_float(a & 0xffff0000u);
        const unsigned bq = cvtpk(y0, y1);
        const float z0 = y0 - __uint_as_float(bq << 16);
        const float z1 = y1 - __uint_as_float(bq & 0xffff0000u);
        w1[p] = a; w2[p] = bq; w3[p] = cvtpk(z0, z1);
    }
    f1 = __builtin_bit_cast(bf16x8, w1);
    f2 = __builtin_bit_cast(bf16x8, w2);
    f3 = __builtin_bit_cast(bf16x8, w3);
}

#define MFMA __builtin_amdgcn_mfma_f32_16x16x32_bf16

// C += A*B via 6 cross products (small-to-large), fp32 accumulate.
__device__ __forceinline__ f32x4 mm6(f32x4 c,
        bf16x8 a1, bf16x8 a2, bf16x8 a3,
        bf16x8 b1, bf16x8 b2, bf16x8 b3) {
    c = MFMA(a3, b1, c, 0, 0, 0);
    c = MFMA(a1, b3, c, 0, 0, 0);
    c = MFMA(a2, b2, c, 0, 0, 0);
    c = MFMA(a2, b1, c, 0, 0, 0);
    c = MFMA(a1, b2, c, 0, 0, 0);
    c = MFMA(a1, b1, c, 0, 0, 0);
    return c;
}

#define ST 35   // At row stride: reads/writes <=2-way on 32 banks

__global__ __launch_bounds__(256, 4) void k_fused(
    const float* __restrict__ feats,   // (256,10,32,64)
    const float* __restrict__ sim,     // (256,19,64,64)
    float* __restrict__ out)           // (2560,32,64)
{
    // At[buf][k*ST + r]: block-local A^T. r: 0-15 = G chans 16rt..16rt+15,
    // 16 = W, 17-31 = zero pad.
    __shared__ __attribute__((aligned(16))) float At[2][64 * ST];

    const int tid  = threadIdx.x;
    const int lane = tid & 63;
    const int ct   = tid >> 6;          // wave = col tile 0..3
    const int lg   = lane >> 4;         // k-subgroup / D-row group
    const int c    = lane & 15;         // col within tile
    const int cb   = 16 * ct + c;       // absolute column
    const int bid  = blockIdx.x;
    const int b    = bid & 255;         // batch; siblings co-XCD
    const int rt   = (bid >> 8) & 1;    // row-group: G chans 16rt..16rt+15
    const int h    = bid >> 9;          // t-half: t = 5h..5h+4

    const float* fb = feats + (size_t)b * 20480;   // 10*32*64
    const float* sb = sim   + (size_t)b * 77824;   // 19*64*64

    // ---- prologue: At[0] = [F_0(rows 16rt..); 1; 0]^T ----
    #pragma unroll
    for (int i = 0; i < 8; ++i) {
        const int idx = i * 256 + tid;  // = r*64 + k, 2048 entries
        const int r = idx >> 6, k = idx & 63;
        float v = 0.f;
        if (r < 16)       v = fb[(16 * rt + r) * 64 + k];
        else if (r == 16) v = 1.0f;
        At[0][k * ST + r] = v;
    }
    __syncthreads();

    // ---- recursion: s=0..8 ----
    for (int s = 0; s < 9; ++s) {
        const float* __restrict__ Mg = sb + (size_t)s * 4096;
        const float* __restrict__ F  = fb + (s + 1) * 2048;

        f32x4 C0, C1;
        #pragma unroll
        for (int i = 0; i < 4; ++i)
            C0[i] = F[(16 * rt + 4 * lg + i) * 64 + cb];   // G rows: +F
        C1 = (f32x4){0.f, 0.f, 0.f, 0.f};
        if (lg == 0) C1[0] = 1.0f;                         // W row: +1

        const float* __restrict__ Atc = At[s & 1];
        #pragma unroll
        for (int kh = 0; kh < 2; ++kh) {
            float xb[8];
            #pragma unroll
            for (int j = 0; j < 8; ++j)
                xb[j] = Mg[(32 * kh + 8 * lg + j) * 64 + cb];   // global, L2-hot
            bf16x8 b1, b2, b3; split8(xb, b1, b2, b3);

            float xa[8];
            #pragma unroll
            for (int j = 0; j < 8; ++j)
                xa[j] = Atc[(32 * kh + 8 * lg + j) * ST + c];        // tile 0
            bf16x8 a1, a2, a3; split8(xa, a1, a2, a3);
            C0 = mm6(C0, a1, a2, a3, b1, b2, b3);

            #pragma unroll
            for (int j = 0; j < 8; ++j)
                xa[j] = Atc[(32 * kh + 8 * lg + j) * ST + 16 + c];   // tile 1
            split8(xa, a1, a2, a3);
            C1 = mm6(C1, a1, a2, a3, b1, b2, b3);
        }

        float* __restrict__ Atn = At[(s + 1) & 1];
        #pragma unroll
        for (int i = 0; i < 4; ++i) {
            Atn[cb * ST +      4 * lg + i] = C0[i];
            Atn[cb * ST + 16 + 4 * lg + i] = C1[i];
        }
        __syncthreads();
    }

    // ---- G fragments once (A_9 in At[1]); idx = kh*2 + tile ----
    bf16x8 g1[4], g2[4], g3[4];
    #pragma unroll
    for (int kh = 0; kh < 2; ++kh)
        #pragma unroll
        for (int tl = 0; tl < 2; ++tl) {
            float xa[8];
            #pragma unroll
            for (int j = 0; j < 8; ++j)
                xa[j] = At[1][(32 * kh + 8 * lg + j) * ST + 16 * tl + c];
            split8(xa, g1[kh * 2 + tl], g2[kh * 2 + tl], g3[kh * 2 + tl]);
        }

    // ---- output: t = 5h..5h+4, barrier-free ----
    for (int s = 0; s < 5; ++s) {
        const int t = 5 * h + s;
        const float* __restrict__ Mg = sb + (size_t)(9 + t) * 4096;

        f32x4 C0 = {0.f, 0.f, 0.f, 0.f};
        f32x4 C1 = C0;
        #pragma unroll
        for (int kh = 0; kh < 2; ++kh) {
            float xb[8];
            #pragma unroll
            for (int j = 0; j < 8; ++j)
                xb[j] = Mg[(32 * kh + 8 * lg + j) * 64 + cb];
            bf16x8 v1, v2, v3; split8(xb, v1, v2, v3);
            C0 = mm6(C0, g1[kh*2+0], g2[kh*2+0], g3[kh*2+0], v1, v2, v3);
            C1 = mm6(C1, g1[kh*2+1], g2[kh*2+1], g3[kh*2+1], v1, v2, v3);
        }

        // W.M_t[cb] = local row 16 = tile1 (lg=0,i=0), lane index c
        const float wv = __shfl(C1[0], lane & 15);
        const float rw = 1.f / (wv + EPSV);

        float* ob = out + ((size_t)b * 10 + t) * 2048;
        #pragma unroll
        for (int i = 0; i < 4; ++i)
            ob[(16 * rt + 4 * lg + i) * 64 + cb] = C0[i] * rw;
    }
}

extern "C" void kernel_launch(void* const* d_in, const int* in_sizes, int n_in,
                              void* d_out, int out_size, void* d_ws, size_t ws_size,
                              hipStream_t stream) {
    const float* feats = (const float*)d_in[0];
    const float* sim   = (const float*)d_in[1];
    k_fused<<<1024, 256, 0, stream>>>(feats, sim, (float*)d_out);
}

// Round 10
// 146.090 us; speedup vs baseline: 1.1471x; 1.0524x over previous
//
#include <hip/hip_runtime.h>

// (B,P,C,H,W)=(256,10,32,8,8); Tm=19, Ta=10, hw=64. All I/O fp32.
// Horner: A_0=[F_0;1]; A_{p+1}=A_p*M_p+[F_{p+1};1] (p=0..8) -> A_9=[G;W]
// out[b,t,c,j] = (G[c,:].M_t[:,j]) / (W.M_t[:,j] + eps)
//
// v20 (from v17, best measured 54us; v18/v19 showed VALU-cy ~ split-count):
// keep v17's minimal-split geometry (grid 512 = b x h, 4 waves = col tiles,
// 3 row-tiles/wave), change the critical path:
//  1. Mb LDS ring dropped -> B read from global with ONE-STEP-AHEAD register
//     prefetch (16 fp32). Loads for s+1 issued before step s's compute; the
//     per-step __syncthreads is a fence, so they can't sink (v12-proven
//     mechanism; v13's failure was 64-reg rings + over-pinning, not this).
//  2. F prefetched identically (8 regs).
//  3. mm9 -> mm6 (absmax-neutral, proven v18/v19): -33% MFMA.
// Output phase barrier-free (W via wave-local shfl), prefetch chain with one
// sched_barrier(0) per step to pin load issue.
// LDS = At[2][64*49] only (25KB). VGPR ~110-130 at (256,2) cap: no spill.

#define EPSV 1e-6f

typedef short  bf16x8 __attribute__((ext_vector_type(8)));
typedef float  f32x4  __attribute__((ext_vector_type(4)));
typedef unsigned int uintx4 __attribute__((ext_vector_type(4)));

__device__ __forceinline__ unsigned cvtpk(float a, float b) {
    unsigned r;
    asm("v_cvt_pk_bf16_f32 %0, %1, %2" : "=v"(r) : "v"(a), "v"(b));
    return r;
}

// exact 3-way split of 8 fp32 -> three bf16x8 fragments (RNE, non-overlap)
__device__ __forceinline__ void split8(const float* x,
                                       bf16x8& f1, bf16x8& f2, bf16x8& f3) {
    uintx4 w1, w2, w3;
    #pragma unroll
    for (int p = 0; p < 4; ++p) {
        const float x0 = x[2 * p], x1 = x[2 * p + 1];
        const unsigned a = cvtpk(x0, x1);
        const float y0 = x0 - __uint_as_float(a << 16);
        const float y1 = x1 - __uint_as_float(a & 0xffff0000u);
        const unsigned bq = cvtpk(y0, y1);
        const float z0 = y0 - __uint_as_float(bq << 16);
        const float z1 = y1 - __uint_as_float(bq & 0xffff0000u);
        w1[p] = a; w2[p] = bq; w3[p] = cvtpk(z0, z1);
    }
    f1 = __builtin_bit_cast(bf16x8, w1);
    f2 = __builtin_bit_cast(bf16x8, w2);
    f3 = __builtin_bit_cast(bf16x8, w3);
}

#define MFMA __builtin_amdgcn_mfma_f32_16x16x32_bf16

// C += A*B via 6 cross products (small-to-large), fp32 accumulate.
__device__ __forceinline__ f32x4 mm6(f32x4 c,
        bf16x8 a1, bf16x8 a2, bf16x8 a3,
        bf16x8 b1, bf16x8 b2, bf16x8 b3) {
    c = MFMA(a3, b1, c, 0, 0, 0);
    c = MFMA(a1, b3, c, 0, 0, 0);
    c = MFMA(a2, b2, c, 0, 0, 0);
    c = MFMA(a2, b1, c, 0, 0, 0);
    c = MFMA(a1, b2, c, 0, 0, 0);
    c = MFMA(a1, b1, c, 0, 0, 0);
    return c;
}

__global__ __launch_bounds__(256, 2) void k_fused(
    const float* __restrict__ feats,   // (256,10,32,64)
    const float* __restrict__ sim,     // (256,19,64,64)
    float* __restrict__ out)           // (2560,32,64)
{
    __shared__ __attribute__((aligned(16))) float At[2][3136];   // 2x 64x49

    const int tid  = threadIdx.x;
    const int lane = tid & 63;
    const int wave = tid >> 6;          // 0..3 = col tile
    const int lg   = lane >> 4;         // k-subgroup / D-row group
    const int c    = lane & 15;         // col within tile
    const int cb   = 16 * wave + c;     // absolute column
    const int b    = blockIdx.x & 255;  // pair (b, b+256) -> same XCD
    const int h    = blockIdx.x >> 8;   // t-half: t = 5h..5h+4

    const float* fb = feats + (size_t)b * 20480;   // 10*32*64
    const float* sb = sim   + (size_t)b * 77824;   // 19*64*64

    // ---- prologue: At[0] = [F_0; 1; 0-pad]^T ----
    {
        const int kk = tid & 63;
        const int r0 = 12 * wave;       // 4 waves x 12 rows = 48
        #pragma unroll
        for (int ii = 0; ii < 12; ++ii) {
            const int r = r0 + ii;
            float v = 0.f;
            if (r < 32)       v = fb[r * 64 + kk];
            else if (r == 32) v = 1.0f;
            At[0][kk * 49 + r] = v;
        }
    }

    // ---- prefetch B for s=0 and F for s=0 (=F_1) ----
    float curb[16], curf[8];
    #pragma unroll
    for (int kh = 0; kh < 2; ++kh)
        #pragma unroll
        for (int j = 0; j < 8; ++j)
            curb[kh * 8 + j] = sb[(32 * kh + 8 * lg + j) * 64 + cb];
    #pragma unroll
    for (int i = 0; i < 4; ++i) {
        curf[i]     = fb[2048 + (     4 * lg + i) * 64 + cb];
        curf[4 + i] = fb[2048 + (16 + 4 * lg + i) * 64 + cb];
    }

    __syncthreads();                    // At[0] visible

    // ---- recursion: s=0..8 ----
    for (int s = 0; s < 9; ++s) {
        // issue next-step loads; the step-ending barrier pins them here.
        float nxb[16], nxf[8];
        {
            const float* __restrict__ Mn =
                sb + (size_t)((s < 8) ? (s + 1) : (9 + 5 * h)) * 4096;
            #pragma unroll
            for (int kh = 0; kh < 2; ++kh)
                #pragma unroll
                for (int j = 0; j < 8; ++j)
                    nxb[kh * 8 + j] = Mn[(32 * kh + 8 * lg + j) * 64 + cb];
        }
        if (s < 8) {
            const float* __restrict__ Fn = fb + (s + 2) * 2048;
            #pragma unroll
            for (int i = 0; i < 4; ++i) {
                nxf[i]     = Fn[(     4 * lg + i) * 64 + cb];
                nxf[4 + i] = Fn[(16 + 4 * lg + i) * 64 + cb];
            }
        }

        f32x4 c0, c1, c2;
        #pragma unroll
        for (int i = 0; i < 4; ++i) { c0[i] = curf[i]; c1[i] = curf[4 + i]; c2[i] = 0.f; }
        if (lg == 0) c2[0] = 1.0f;                   // W row: F == 1

        const float* __restrict__ Atc = At[s & 1];
        #pragma unroll
        for (int kh = 0; kh < 2; ++kh) {
            bf16x8 b1, b2, b3; split8(&curb[kh * 8], b1, b2, b3);

            float xa[8];
            bf16x8 a1, a2, a3;
            #pragma unroll
            for (int j = 0; j < 8; ++j)
                xa[j] = Atc[(32 * kh + 8 * lg + j) * 49 + c];
            split8(xa, a1, a2, a3);
            c0 = mm6(c0, a1, a2, a3, b1, b2, b3);
            #pragma unroll
            for (int j = 0; j < 8; ++j)
                xa[j] = Atc[(32 * kh + 8 * lg + j) * 49 + 16 + c];
            split8(xa, a1, a2, a3);
            c1 = mm6(c1, a1, a2, a3, b1, b2, b3);
            #pragma unroll
            for (int j = 0; j < 8; ++j)
                xa[j] = Atc[(32 * kh + 8 * lg + j) * 49 + 32 + c];
            split8(xa, a1, a2, a3);
            c2 = mm6(c2, a1, a2, a3, b1, b2, b3);
        }

        // writeback A_{s+1}^T into the other buffer
        float* __restrict__ Atn = At[(s + 1) & 1];
        #pragma unroll
        for (int i = 0; i < 4; ++i) {
            Atn[cb * 49 +      4 * lg + i] = c0[i];
            Atn[cb * 49 + 16 + 4 * lg + i] = c1[i];
            Atn[cb * 49 + 32 + 4 * lg + i] = c2[i];
        }
        __syncthreads();

        #pragma unroll
        for (int q = 0; q < 16; ++q) curb[q] = nxb[q];
        if (s < 8) {
            #pragma unroll
            for (int q = 0; q < 8; ++q) curf[q] = nxf[q];
        }
    }

    // ---- build G fragments once (A_9 lives in At[1]) ----
    bf16x8 g1[6], g2[6], g3[6];        // idx = kh*3 + rt
    #pragma unroll
    for (int kh = 0; kh < 2; ++kh)
        #pragma unroll
        for (int rt = 0; rt < 3; ++rt) {
            float xa[8];
            #pragma unroll
            for (int j = 0; j < 8; ++j)
                xa[j] = At[1][(32 * kh + 8 * lg + j) * 49 + 16 * rt + c];
            split8(xa, g1[kh * 3 + rt], g2[kh * 3 + rt], g3[kh * 3 + rt]);
        }

    // ---- output: t = 5h..5h+4, barrier-free, prefetch-chained ----
    for (int s = 0; s < 5; ++s) {
        float nxb[16];
        if (s < 4) {
            const float* __restrict__ Mn = sb + (size_t)(10 + 5 * h + s) * 4096;
            #pragma unroll
            for (int kh = 0; kh < 2; ++kh)
                #pragma unroll
                for (int j = 0; j < 8; ++j)
                    nxb[kh * 8 + j] = Mn[(32 * kh + 8 * lg + j) * 64 + cb];
        }
        __builtin_amdgcn_sched_barrier(0);   // pin issue before compute

        f32x4 c0 = {0.f, 0.f, 0.f, 0.f};
        f32x4 c1 = c0, c2 = c0;
        #pragma unroll
        for (int kh = 0; kh < 2; ++kh) {
            bf16x8 v1, v2, v3; split8(&curb[kh * 8], v1, v2, v3);
            c0 = mm6(c0, g1[kh*3+0], g2[kh*3+0], g3[kh*3+0], v1, v2, v3);
            c1 = mm6(c1, g1[kh*3+1], g2[kh*3+1], g3[kh*3+1], v1, v2, v3);
            c2 = mm6(c2, g1[kh*3+2], g2[kh*3+2], g3[kh*3+2], v1, v2, v3);
        }

        // W.M_t sits in c2[0] of lane-group 0 (row 32); wave-local broadcast
        const float wv = __shfl(c2[0], lane & 15);
        const float rw = 1.f / (wv + EPSV);

        float* ob = out + ((size_t)b * 10 + 5 * h + s) * 2048;
        #pragma unroll
        for (int i = 0; i < 4; ++i) {
            ob[(     4 * lg + i) * 64 + cb] = c0[i] * rw;
            ob[(16 + 4 * lg + i) * 64 + cb] = c1[i] * rw;
        }

        if (s < 4) {
            #pragma unroll
            for (int q = 0; q < 16; ++q) curb[q] = nxb[q];
        }
    }
}

extern "C" void kernel_launch(void* const* d_in, const int* in_sizes, int n_in,
                              void* d_out, int out_size, void* d_ws, size_t ws_size,
                              hipStream_t stream) {
    const float* feats = (const float*)d_in[0];
    const float* sim   = (const float*)d_in[1];
    k_fused<<<512, 256, 0, stream>>>(feats, sim, (float*)d_out);
}